// Round 7
// baseline (174.465 us; speedup 1.0000x reference)
//
#include <hip/hip_runtime.h>
#include <float.h>

// Problem constants (from reference setup_inputs)
#define B_SZ 2
#define N_SZ 16384                  // N == M
#define E_SZ 49152

#define TPB 512
#define WAVES (TPB / 64)            // 8
#define ROWS_PER_BLOCK 256          // 8 waves x 32 rows
#define MSPLIT 2
#define MRANGE (N_SZ / MSPLIT)      // 8192 cols per block
#define CHUNK 512                   // target points per LDS chunk
#define NCHUNK (MRANGE / CHUNK)     // 16
#define TILES_PER_CHUNK (CHUNK / 32) // 16 (4 groups of 4)

#define CH_BLOCKS (2 * (B_SZ * N_SZ / ROWS_PER_BLOCK) * MSPLIT)  // 512
#define EDGE_BLOCKS (B_SZ * E_SZ / TPB)                          // 192
#define NROWS_TOT (2 * B_SZ * N_SZ)                              // 65536

// frag workspace: per dir, per batch: plane0 [16384 x 16B] then plane1
#define PLANE_BYTES (N_SZ * 16)                  // 256 KB
#define BATCH_FRAG_BYTES (2 * PLANE_BYTES)       // 512 KB
#define DIR_FRAG_BYTES (B_SZ * BATCH_FRAG_BYTES) // 1 MB
#define MINS_OFF (2 * DIR_FRAG_BYTES)            // 2 MB
#define SUMS_OFF (MINS_OFF + NROWS_TOT * 4)      // +256 KB

typedef short short8 __attribute__((ext_vector_type(8)));
typedef float f32x16 __attribute__((ext_vector_type(16)));

// ---- bf16 bit helpers (RNE); inputs are finite Gaussians ----
__device__ inline short f2bf(float f) {
    unsigned u = __float_as_uint(f);
    unsigned r = (u + 0x7fffu + ((u >> 16) & 1u)) >> 16;
    return (short)r;
}
__device__ inline float bf2f(short s) {
    return __uint_as_float(((unsigned)(unsigned short)s) << 16);
}

// ---- sortable-uint mapping for float atomicMin (handles negatives) ----
__device__ inline unsigned fmapu(float f) {
    unsigned u = __float_as_uint(f);
    return ((int)u < 0) ? ~u : (u ^ 0x80000000u);
}
__device__ inline float funmapu(unsigned v) {
    unsigned b = ((int)v < 0) ? (v ^ 0x80000000u) : ~v;
    return __uint_as_float(b);
}

// ---- prep: point -> B-operand fragments; init minOut + sums ----
// B-rep per point t: plane0 (k0-7): {thx,thy,thz, thx,thy,thz, 1, 1}
//                    plane1 (k8-15): {tlx,tly,tlz, t2h,t2l, 0,0,0}
// idx 0..32767: tgt -> dir0 frag buffer; 32768..65535: pred -> dir1.
__global__ __launch_bounds__(TPB) void prep(const float* __restrict__ pred,
                                            const float* __restrict__ tgt,
                                            char* __restrict__ ws) {
    int idx = blockIdx.x * TPB + threadIdx.x;       // 0..131071
    if (blockIdx.x == 0 && threadIdx.x < 6)
        ((double*)(ws + SUMS_OFF))[threadIdx.x] = 0.0;
    if (idx < NROWS_TOT) ((unsigned*)(ws + MINS_OFF))[idx] = 0xFFFFFFFFu;
    if (idx >= 2 * B_SZ * N_SZ) return;

    const bool isTgt = idx < B_SZ * N_SZ;
    int row = isTgt ? idx : idx - B_SZ * N_SZ;      // 0..32767
    int batch = row >> 14, pt = row & (N_SZ - 1);
    const float* src = (isTgt ? tgt : pred) + (size_t)row * 3;
    char* base = ws + (isTgt ? 0 : DIR_FRAG_BYTES) + (size_t)batch * BATCH_FRAG_BYTES;

    float tx = src[0], ty = src[1], tz = src[2];
    short hx = f2bf(tx), hy = f2bf(ty), hz = f2bf(tz);
    short lx = f2bf(tx - bf2f(hx)), ly = f2bf(ty - bf2f(hy)), lz = f2bf(tz - bf2f(hz));
    float t2 = fmaf(tx, tx, fmaf(ty, ty, tz * tz));
    short t2h = f2bf(t2), t2l = f2bf(t2 - bf2f(t2h));
    const short one = 0x3f80;

    *(short8*)(base + (size_t)pt * 16) = (short8){hx, hy, hz, hx, hy, hz, one, one};
    *(short8*)(base + PLANE_BYTES + (size_t)pt * 16) =
        (short8){lx, ly, lz, t2h, t2l, 0, 0, 0};
}

// ---- main: chamfer partial row-mins (M split in 2) + edge loss ----
// d^2 = (-2p).t + p^2 + t^2, K=13 bf16 hi/lo split, one 32x32x16 MFMA/tile.
// A lane: m=lane&31, k=(lane>>5)*8+j (same half convention both operands):
//   half0 (k0-7):  {ahx,ahy,ahz, alx,aly,alz, p2h,p2l}   (a = -2p)
//   half1 (k8-15): {ahx,ahy,ahz, 1, 1, 0,0,0}
// C/D (m74/m101): col=lane&31, row=(reg&3)+8*(reg>>2)+4*(lane>>5).
__global__ __launch_bounds__(TPB, 4) void main_kernel(
    const float* __restrict__ pred, const float* __restrict__ tgt,
    const int* __restrict__ edges, char* __restrict__ ws)
{
    __shared__ __align__(16) char sB[2][2 * CHUNK * 16];   // 2 x 16 KB
    __shared__ float wred[WAVES], wred2[WAVES];
    double* sums = (double*)(ws + SUMS_OFF);
    unsigned* minOut = (unsigned*)(ws + MINS_OFF);
    const int lane = threadIdx.x & 63;
    const int wv = threadIdx.x >> 6;

    if (blockIdx.x < CH_BLOCKS) {
        const int dir = blockIdx.x >> 8;          // 0: rows=pred, search tgt
        const int rest = blockIdx.x & 255;
        const int ms = rest >> 7;                 // which M half
        const int xb = rest & 127;
        const int batch = xb >> 6;
        const int rowInB = (xb & 63) * ROWS_PER_BLOCK;
        const float* P = dir ? tgt : pred;
        const char* fragBase = ws + (size_t)dir * DIR_FRAG_BYTES
                                  + (size_t)batch * BATCH_FRAG_BYTES;
        const int mBase = ms * MRANGE;
        const int bl = lane & 31;
        const int half = lane >> 5;

        // ---- A fragment (one 32-row tile per wave) ----
        int r = batch * N_SZ + rowInB + wv * 32 + bl;
        const float* p = P + (size_t)r * 3;
        float px = p[0], py = p[1], pz = p[2];
        float ax = -2.f * px, ay = -2.f * py, az = -2.f * pz;
        short ahx = f2bf(ax), ahy = f2bf(ay), ahz = f2bf(az);
        short alx = f2bf(ax - bf2f(ahx)), aly = f2bf(ay - bf2f(ahy)),
              alz = f2bf(az - bf2f(ahz));
        float p2 = fmaf(px, px, fmaf(py, py, pz * pz));
        short p2h = f2bf(p2), p2l = f2bf(p2 - bf2f(p2h));
        const short one = 0x3f80;
        short8 af = half == 0
            ? (short8){ahx, ahy, ahz, alx, aly, alz, p2h, p2l}
            : (short8){ahx, ahy, ahz, one, one, 0, 0, 0};

        // ---- staging: 16 KB/chunk, 32 B/thread ----
        const int t = threadIdx.x;
        float4 st0, st1;
        auto ldChunk = [&](int c) {
            const float4* s0 = (const float4*)(fragBase + (size_t)(mBase + c * CHUNK) * 16);
            const float4* s1 = (const float4*)(fragBase + PLANE_BYTES
                                               + (size_t)(mBase + c * CHUNK) * 16);
            st0 = s0[t]; st1 = s1[t];
        };
        auto wrChunk = [&](int buf) {
            float4* d = (float4*)sB[buf];
            d[t] = st0; d[t + TPB] = st1;
        };

        float nmin[16];
        #pragma unroll
        for (int e = 0; e < 16; e++) nmin[e] = FLT_MAX;
        const f32x16 zc = {0.f, 0.f, 0.f, 0.f, 0.f, 0.f, 0.f, 0.f,
                           0.f, 0.f, 0.f, 0.f, 0.f, 0.f, 0.f, 0.f};

        ldChunk(0); wrChunk(0);
        __syncthreads();

        for (int c = 0; c < NCHUNK; c++) {
            int buf = c & 1;
            if (c + 1 < NCHUNK) ldChunk(c + 1);     // issue early, no wait yet
            const char* bp = sB[buf] + half * (CHUNK * 16) + bl * 16;
            for (int g = 0; g < TILES_PER_CHUNK / 4; g++) {   // 4 groups of 4 tiles
                short8 b0 = *(const short8*)(bp + (g * 128 + 0) * 16);
                short8 b1 = *(const short8*)(bp + (g * 128 + 32) * 16);
                short8 b2 = *(const short8*)(bp + (g * 128 + 64) * 16);
                short8 b3 = *(const short8*)(bp + (g * 128 + 96) * 16);
                f32x16 r0 = __builtin_amdgcn_mfma_f32_32x32x16_bf16(af, b0, zc, 0, 0, 0);
                f32x16 r1 = __builtin_amdgcn_mfma_f32_32x32x16_bf16(af, b1, zc, 0, 0, 0);
                f32x16 r2 = __builtin_amdgcn_mfma_f32_32x32x16_bf16(af, b2, zc, 0, 0, 0);
                f32x16 r3 = __builtin_amdgcn_mfma_f32_32x32x16_bf16(af, b3, zc, 0, 0, 0);
                #pragma unroll
                for (int e = 0; e < 16; e++) {
                    float u = fminf(r0[e], r1[e]);
                    float v = fminf(r2[e], r3[e]);
                    nmin[e] = fminf(fminf(u, v), nmin[e]);
                }
            }
            if (c + 1 < NCHUNK) wrChunk(buf ^ 1);   // waits vmcnt internally
            __syncthreads();
        }

        // ---- epilogue: fold 32 col-lanes, atomicMin partial per row ----
        float vals[16];
        #pragma unroll
        for (int e = 0; e < 16; e++) {
            float v = nmin[e];
            v = fminf(v, __shfl_xor(v, 1));
            v = fminf(v, __shfl_xor(v, 2));
            v = fminf(v, __shfl_xor(v, 4));
            v = fminf(v, __shfl_xor(v, 8));
            v = fminf(v, __shfl_xor(v, 16));
            vals[e] = v;
        }
        if (bl == 0) {
            int base = dir * (B_SZ * N_SZ) + batch * N_SZ + rowInB + wv * 32 + half * 4;
            #pragma unroll
            for (int e = 0; e < 16; e++) {
                int rrow = (e & 3) + 8 * (e >> 2);
                atomicMin(&minOut[base + rrow], fmapu(vals[e]));
            }
        }
    } else {
        // ---- edge loss (int32 edges per harness convention) ----
        int idx = (blockIdx.x - CH_BLOCKS) * TPB + threadIdx.x;  // 0..98303
        int b = idx >= E_SZ;                        // block-uniform (96 blocks/b)
        int e = idx - b * E_SZ;
        int2 ee = ((const int2*)edges)[e];
        const float* p0 = pred + ((size_t)b * N_SZ + (size_t)ee.x) * 3;
        const float* p1 = pred + ((size_t)b * N_SZ + (size_t)ee.y) * 3;
        float dx = p0[0] - p1[0], dy = p0[1] - p1[1], dz = p0[2] - p1[2];
        float len = sqrtf(dx * dx + dy * dy + dz * dz);
        float s = len, q = len * len;
        for (int o = 32; o > 0; o >>= 1) {
            s += __shfl_down(s, o, 64);
            q += __shfl_down(q, o, 64);
        }
        if (lane == 0) { wred[wv] = s; wred2[wv] = q; }
        __syncthreads();
        if (threadIdx.x == 0) {
            float ts = 0.f, tq = 0.f;
            #pragma unroll
            for (int w = 0; w < WAVES; w++) { ts += wred[w]; tq += wred2[w]; }
            atomicAdd(&sums[2 + 2 * b], (double)ts);
            atomicAdd(&sums[3 + 2 * b], (double)tq);
        }
    }
}

// ---- final: sqrt+mean of 65536 row-mins (one block) + combine outputs ----
#define FIN_TPB 1024
__global__ __launch_bounds__(FIN_TPB) void final_kernel(const char* __restrict__ ws,
                                                        float* __restrict__ out) {
    const uint4* mins = (const uint4*)(ws + MINS_OFF);   // 16384 uint4
    const double* sums = (const double*)(ws + SUMS_OFF);
    __shared__ double redA[FIN_TPB / 64], redB[FIN_TPB / 64];

    float sA = 0.f, sB = 0.f;      // per-thread: 64 rows -> fp32 safe
    #pragma unroll
    for (int i = 0; i < 16; i++) {
        uint4 v = mins[i * FIN_TPB + threadIdx.x];
        float s = sqrtf(fmaxf(funmapu(v.x), 0.f)) + sqrtf(fmaxf(funmapu(v.y), 0.f))
                + sqrtf(fmaxf(funmapu(v.z), 0.f)) + sqrtf(fmaxf(funmapu(v.w), 0.f));
        if (i < 8) sA += s; else sB += s;   // first 32768 rows = dir0
    }
    for (int o = 32; o > 0; o >>= 1) {
        sA += __shfl_down(sA, o, 64);
        sB += __shfl_down(sB, o, 64);
    }
    int wv = threadIdx.x >> 6, ln = threadIdx.x & 63;
    if (ln == 0) { redA[wv] = (double)sA; redB[wv] = (double)sB; }
    __syncthreads();
    if (threadIdx.x == 0) {
        double tA = 0.0, tB = 0.0;
        #pragma unroll
        for (int w = 0; w < FIN_TPB / 64; w++) { tA += redA[w]; tB += redB[w]; }
        double c = tA / (double)(B_SZ * N_SZ) + tB / (double)(B_SZ * N_SZ);
        double e = 0.0;
        #pragma unroll
        for (int b = 0; b < B_SZ; b++) {
            double s = sums[2 + 2 * b], q = sums[3 + 2 * b];
            e += (q - s * s / (double)E_SZ) / (double)(E_SZ - 1);
        }
        e *= (1.0 / B_SZ);
        double tot = 1.0 * c + 0.1 * e;
        out[0] = (float)tot;
        out[1] = (float)c;
        out[2] = (float)e;
    }
}

extern "C" void kernel_launch(void* const* d_in, const int* in_sizes, int n_in,
                              void* d_out, int out_size, void* d_ws, size_t ws_size,
                              hipStream_t stream) {
    const float* pred = (const float*)d_in[0];       // (B, N, 3) fp32
    const float* tgt  = (const float*)d_in[1];       // (B, M, 3) fp32
    const int* edges  = (const int*)d_in[2];         // (E, 2) int32 (harness-converted)
    float* out = (float*)d_out;
    char* ws = (char*)d_ws;                          // needs ~2.3 MB

    // 1) fragments + minOut/sums init
    prep<<<dim3((2 * B_SZ * N_SZ) / TPB), TPB, 0, stream>>>(pred, tgt, ws);

    // 2) chamfer partial mins (512 blocks) + edge (192 blocks)
    main_kernel<<<dim3(CH_BLOCKS + EDGE_BLOCKS), TPB, 0, stream>>>(
        pred, tgt, edges, ws);

    // 3) finalize + combine (single block)
    final_kernel<<<dim3(1), FIN_TPB, 0, stream>>>(ws, out);
}

// Round 8
// 108.899 us; speedup vs baseline: 1.6021x; 1.6021x over previous
//
#include <hip/hip_runtime.h>
#include <float.h>

// Problem constants (from reference setup_inputs)
#define B_SZ 2
#define N_SZ 16384                  // N == M
#define E_SZ 49152

#define TPB 512
#define WAVES (TPB / 64)            // 8
#define ROWS_PER_BLOCK 256          // 8 waves x 32 rows
#define MSPLIT 2
#define MRANGE (N_SZ / MSPLIT)      // 8192 cols per block
#define CHUNK 512                   // target points per LDS chunk
#define NCHUNK (MRANGE / CHUNK)     // 16
#define TILES_PER_CHUNK (CHUNK / 32) // 16

#define CH_BLOCKS (2 * (B_SZ * N_SZ / ROWS_PER_BLOCK) * MSPLIT)  // 512
#define EDGE_BLOCKS (B_SZ * E_SZ / TPB)                          // 192
#define NROWS_TOT (2 * B_SZ * N_SZ)                              // 65536

// frag workspace: per dir, per batch: plane0 [16384 x 16B] then plane1
#define PLANE_BYTES (N_SZ * 16)                  // 256 KB
#define BATCH_FRAG_BYTES (2 * PLANE_BYTES)       // 512 KB
#define DIR_FRAG_BYTES (B_SZ * BATCH_FRAG_BYTES) // 1 MB
#define MINS_OFF (2 * DIR_FRAG_BYTES)            // 2 MB
#define SUMS_OFF (MINS_OFF + NROWS_TOT * 4)      // +256 KB

typedef short short8 __attribute__((ext_vector_type(8)));
typedef float f32x16 __attribute__((ext_vector_type(16)));

// ---- bf16 bit helpers (RNE); inputs are finite Gaussians ----
__device__ inline short f2bf(float f) {
    unsigned u = __float_as_uint(f);
    unsigned r = (u + 0x7fffu + ((u >> 16) & 1u)) >> 16;
    return (short)r;
}
__device__ inline float bf2f(short s) {
    return __uint_as_float(((unsigned)(unsigned short)s) << 16);
}

// ---- sortable-uint mapping for float atomicMin (handles negatives) ----
__device__ inline unsigned fmapu(float f) {
    unsigned u = __float_as_uint(f);
    return ((int)u < 0) ? ~u : (u ^ 0x80000000u);
}
__device__ inline float funmapu(unsigned v) {
    unsigned b = ((int)v < 0) ? (v ^ 0x80000000u) : ~v;
    return __uint_as_float(b);
}

// ---- prep: point -> B-operand fragments; init minOut + sums ----
// B-rep per point t: plane0 (k0-7): {thx,thy,thz, thx,thy,thz, 1, 1}
//                    plane1 (k8-15): {tlx,tly,tlz, t2h,t2l, 0,0,0}
// idx 0..32767: tgt -> dir0 frag buffer; 32768..65535: pred -> dir1.
__global__ __launch_bounds__(TPB) void prep(const float* __restrict__ pred,
                                            const float* __restrict__ tgt,
                                            char* __restrict__ ws) {
    int idx = blockIdx.x * TPB + threadIdx.x;       // 0..131071
    if (blockIdx.x == 0 && threadIdx.x < 6)
        ((double*)(ws + SUMS_OFF))[threadIdx.x] = 0.0;
    if (idx < NROWS_TOT) ((unsigned*)(ws + MINS_OFF))[idx] = 0xFFFFFFFFu;
    if (idx >= 2 * B_SZ * N_SZ) return;

    const bool isTgt = idx < B_SZ * N_SZ;
    int row = isTgt ? idx : idx - B_SZ * N_SZ;      // 0..32767
    int batch = row >> 14, pt = row & (N_SZ - 1);
    const float* src = (isTgt ? tgt : pred) + (size_t)row * 3;
    char* base = ws + (isTgt ? 0 : DIR_FRAG_BYTES) + (size_t)batch * BATCH_FRAG_BYTES;

    float tx = src[0], ty = src[1], tz = src[2];
    short hx = f2bf(tx), hy = f2bf(ty), hz = f2bf(tz);
    short lx = f2bf(tx - bf2f(hx)), ly = f2bf(ty - bf2f(hy)), lz = f2bf(tz - bf2f(hz));
    float t2 = fmaf(tx, tx, fmaf(ty, ty, tz * tz));
    short t2h = f2bf(t2), t2l = f2bf(t2 - bf2f(t2h));
    const short one = 0x3f80;

    *(short8*)(base + (size_t)pt * 16) = (short8){hx, hy, hz, hx, hy, hz, one, one};
    *(short8*)(base + PLANE_BYTES + (size_t)pt * 16) =
        (short8){lx, ly, lz, t2h, t2l, 0, 0, 0};
}

// ---- main: chamfer partial row-mins (M split in 2) + edge loss ----
// d^2 = (-2p).t + p^2 + t^2, K=13 bf16 hi/lo split, one 32x32x16 MFMA/tile.
// A lane: m=lane&31, k=(lane>>5)*8+j (same half convention both operands):
//   half0 (k0-7):  {ahx,ahy,ahz, alx,aly,alz, p2h,p2l}   (a = -2p)
//   half1 (k8-15): {ahx,ahy,ahz, 1, 1, 0,0,0}
// C/D: col=lane&31, row=(reg&3)+8*(reg>>2)+4*(lane>>5)  [verified: R7 absmax 0]
// NOTE R7->R8: 4-MFMA groups + __launch_bounds__(,4) cap=128 unified regs
// caused AGPR spill (157 MB scratch WRITE). 2-groups + no cap = R6-proven 56.
__global__ __launch_bounds__(TPB, 1) void main_kernel(
    const float* __restrict__ pred, const float* __restrict__ tgt,
    const int* __restrict__ edges, char* __restrict__ ws)
{
    __shared__ __align__(16) char sB[2][2 * CHUNK * 16];   // 2 x 16 KB
    __shared__ float wred[WAVES], wred2[WAVES];
    double* sums = (double*)(ws + SUMS_OFF);
    unsigned* minOut = (unsigned*)(ws + MINS_OFF);
    const int lane = threadIdx.x & 63;
    const int wv = threadIdx.x >> 6;

    if (blockIdx.x < CH_BLOCKS) {
        const int dir = blockIdx.x >> 8;          // 0: rows=pred, search tgt
        const int rest = blockIdx.x & 255;
        const int ms = rest >> 7;                 // which M half
        const int xb = rest & 127;
        const int batch = xb >> 6;
        const int rowInB = (xb & 63) * ROWS_PER_BLOCK;
        const float* P = dir ? tgt : pred;
        const char* fragBase = ws + (size_t)dir * DIR_FRAG_BYTES
                                  + (size_t)batch * BATCH_FRAG_BYTES;
        const int mBase = ms * MRANGE;
        const int bl = lane & 31;
        const int half = lane >> 5;

        // ---- A fragment (one 32-row tile per wave) ----
        int r = batch * N_SZ + rowInB + wv * 32 + bl;
        const float* p = P + (size_t)r * 3;
        float px = p[0], py = p[1], pz = p[2];
        float ax = -2.f * px, ay = -2.f * py, az = -2.f * pz;
        short ahx = f2bf(ax), ahy = f2bf(ay), ahz = f2bf(az);
        short alx = f2bf(ax - bf2f(ahx)), aly = f2bf(ay - bf2f(ahy)),
              alz = f2bf(az - bf2f(ahz));
        float p2 = fmaf(px, px, fmaf(py, py, pz * pz));
        short p2h = f2bf(p2), p2l = f2bf(p2 - bf2f(p2h));
        const short one = 0x3f80;
        short8 af = half == 0
            ? (short8){ahx, ahy, ahz, alx, aly, alz, p2h, p2l}
            : (short8){ahx, ahy, ahz, one, one, 0, 0, 0};

        // ---- staging: 16 KB/chunk, 32 B/thread ----
        const int t = threadIdx.x;
        float4 st0, st1;
        auto ldChunk = [&](int c) {
            const float4* s0 = (const float4*)(fragBase + (size_t)(mBase + c * CHUNK) * 16);
            const float4* s1 = (const float4*)(fragBase + PLANE_BYTES
                                               + (size_t)(mBase + c * CHUNK) * 16);
            st0 = s0[t]; st1 = s1[t];
        };
        auto wrChunk = [&](int buf) {
            float4* d = (float4*)sB[buf];
            d[t] = st0; d[t + TPB] = st1;
        };

        float nmin[16];
        #pragma unroll
        for (int e = 0; e < 16; e++) nmin[e] = FLT_MAX;
        const f32x16 zc = {0.f, 0.f, 0.f, 0.f, 0.f, 0.f, 0.f, 0.f,
                           0.f, 0.f, 0.f, 0.f, 0.f, 0.f, 0.f, 0.f};

        ldChunk(0); wrChunk(0);
        __syncthreads();

        for (int c = 0; c < NCHUNK; c++) {
            int buf = c & 1;
            if (c + 1 < NCHUNK) ldChunk(c + 1);     // issue early, no wait yet
            const char* bp = sB[buf] + half * (CHUNK * 16) + bl * 16;
            #pragma unroll 2
            for (int mt = 0; mt < TILES_PER_CHUNK; mt += 2) {
                short8 b0 = *(const short8*)(bp + (mt * 32) * 16);
                short8 b1 = *(const short8*)(bp + (mt * 32 + 32) * 16);
                f32x16 r0 = __builtin_amdgcn_mfma_f32_32x32x16_bf16(af, b0, zc, 0, 0, 0);
                f32x16 r1 = __builtin_amdgcn_mfma_f32_32x32x16_bf16(af, b1, zc, 0, 0, 0);
                #pragma unroll
                for (int e = 0; e < 16; e++)
                    nmin[e] = fminf(fminf(r0[e], r1[e]), nmin[e]);
            }
            if (c + 1 < NCHUNK) wrChunk(buf ^ 1);   // waits vmcnt internally
            __syncthreads();
        }

        // ---- epilogue: fold 32 col-lanes, atomicMin partial per row ----
        float vals[16];
        #pragma unroll
        for (int e = 0; e < 16; e++) {
            float v = nmin[e];
            v = fminf(v, __shfl_xor(v, 1));
            v = fminf(v, __shfl_xor(v, 2));
            v = fminf(v, __shfl_xor(v, 4));
            v = fminf(v, __shfl_xor(v, 8));
            v = fminf(v, __shfl_xor(v, 16));
            vals[e] = v;
        }
        if (bl == 0) {
            int base = dir * (B_SZ * N_SZ) + batch * N_SZ + rowInB + wv * 32 + half * 4;
            #pragma unroll
            for (int e = 0; e < 16; e++) {
                int rrow = (e & 3) + 8 * (e >> 2);
                atomicMin(&minOut[base + rrow], fmapu(vals[e]));
            }
        }
    } else {
        // ---- edge loss (int32 edges per harness convention) ----
        int idx = (blockIdx.x - CH_BLOCKS) * TPB + threadIdx.x;  // 0..98303
        int b = idx >= E_SZ;                        // block-uniform (96 blocks/b)
        int e = idx - b * E_SZ;
        int2 ee = ((const int2*)edges)[e];
        const float* p0 = pred + ((size_t)b * N_SZ + (size_t)ee.x) * 3;
        const float* p1 = pred + ((size_t)b * N_SZ + (size_t)ee.y) * 3;
        float dx = p0[0] - p1[0], dy = p0[1] - p1[1], dz = p0[2] - p1[2];
        float len = sqrtf(dx * dx + dy * dy + dz * dz);
        float s = len, q = len * len;
        for (int o = 32; o > 0; o >>= 1) {
            s += __shfl_down(s, o, 64);
            q += __shfl_down(q, o, 64);
        }
        if (lane == 0) { wred[wv] = s; wred2[wv] = q; }
        __syncthreads();
        if (threadIdx.x == 0) {
            float ts = 0.f, tq = 0.f;
            #pragma unroll
            for (int w = 0; w < WAVES; w++) { ts += wred[w]; tq += wred2[w]; }
            atomicAdd(&sums[2 + 2 * b], (double)ts);
            atomicAdd(&sums[3 + 2 * b], (double)tq);
        }
    }
}

// ---- final: sqrt+mean of 65536 row-mins (one block) + combine outputs ----
#define FIN_TPB 1024
__global__ __launch_bounds__(FIN_TPB) void final_kernel(const char* __restrict__ ws,
                                                        float* __restrict__ out) {
    const uint4* mins = (const uint4*)(ws + MINS_OFF);   // 16384 uint4
    const double* sums = (const double*)(ws + SUMS_OFF);
    __shared__ double redA[FIN_TPB / 64], redB[FIN_TPB / 64];

    float sA = 0.f, sB = 0.f;      // per-thread: 64 rows -> fp32 safe
    #pragma unroll
    for (int i = 0; i < 16; i++) {
        uint4 v = mins[i * FIN_TPB + threadIdx.x];
        float s = sqrtf(fmaxf(funmapu(v.x), 0.f)) + sqrtf(fmaxf(funmapu(v.y), 0.f))
                + sqrtf(fmaxf(funmapu(v.z), 0.f)) + sqrtf(fmaxf(funmapu(v.w), 0.f));
        if (i < 8) sA += s; else sB += s;   // first 32768 rows = dir0
    }
    for (int o = 32; o > 0; o >>= 1) {
        sA += __shfl_down(sA, o, 64);
        sB += __shfl_down(sB, o, 64);
    }
    int wv = threadIdx.x >> 6, ln = threadIdx.x & 63;
    if (ln == 0) { redA[wv] = (double)sA; redB[wv] = (double)sB; }
    __syncthreads();
    if (threadIdx.x == 0) {
        double tA = 0.0, tB = 0.0;
        #pragma unroll
        for (int w = 0; w < FIN_TPB / 64; w++) { tA += redA[w]; tB += redB[w]; }
        double c = tA / (double)(B_SZ * N_SZ) + tB / (double)(B_SZ * N_SZ);
        double e = 0.0;
        #pragma unroll
        for (int b = 0; b < B_SZ; b++) {
            double s = sums[2 + 2 * b], q = sums[3 + 2 * b];
            e += (q - s * s / (double)E_SZ) / (double)(E_SZ - 1);
        }
        e *= (1.0 / B_SZ);
        double tot = 1.0 * c + 0.1 * e;
        out[0] = (float)tot;
        out[1] = (float)c;
        out[2] = (float)e;
    }
}

extern "C" void kernel_launch(void* const* d_in, const int* in_sizes, int n_in,
                              void* d_out, int out_size, void* d_ws, size_t ws_size,
                              hipStream_t stream) {
    const float* pred = (const float*)d_in[0];       // (B, N, 3) fp32
    const float* tgt  = (const float*)d_in[1];       // (B, M, 3) fp32
    const int* edges  = (const int*)d_in[2];         // (E, 2) int32 (harness-converted)
    float* out = (float*)d_out;
    char* ws = (char*)d_ws;                          // needs ~2.3 MB

    // 1) fragments + minOut/sums init
    prep<<<dim3((2 * B_SZ * N_SZ) / TPB), TPB, 0, stream>>>(pred, tgt, ws);

    // 2) chamfer partial mins (512 blocks) + edge (192 blocks)
    main_kernel<<<dim3(CH_BLOCKS + EDGE_BLOCKS), TPB, 0, stream>>>(
        pred, tgt, edges, ws);

    // 3) finalize + combine (single block)
    final_kernel<<<dim3(1), FIN_TPB, 0, stream>>>(ws, out);
}